// Round 8
// baseline (551.055 us; speedup 1.0000x reference)
//
#include <hip/hip_runtime.h>
#include <hip/hip_bf16.h>
#include <cstdint>

// DiT block: B=8, N=1024, HID=1024, NH=16, HD=64, MLP=4096.
// R14: R13's 2-slot-per-tile K-loop re-derived for 2-deep buffering so
// LDS stays at the proven 96KB (R13's 144KB 3-buffer request is the
// prime suspect for the container failure). Per tile: slot1 {reads,
// lgkm0, half the MFMAs}, slot2 {last reads, lgkm0, BAR, stage t+2
// into freed buf, vmcnt(6) [drains t+1, staged a full tile ago ->
// latency hidden], BAR, rest of MFMAs}. 2 barriers + 1 vmcnt per tile
// vs R10's 8+2. ds_reads at 16/wave/tile minimum (fragment reuse).
// Attention = R12 8-wave (worked). Epilogues/XCD decode unchanged.

typedef __bf16 bf16;
typedef __attribute__((ext_vector_type(8))) __bf16 bf16x8;
typedef __attribute__((ext_vector_type(4))) __bf16 bf16x4;
typedef __attribute__((ext_vector_type(4))) float f32x4;

#define SEQ   1024
#define NHID  1024
#define NHEAD 16
#define HDIM  64
#define CMS   6144          // cmod row stride

// async 16B global->LDS: lds dest = wave-uniform base + lane*16
#define GLD16(gp, lp)                                                  \
  __builtin_amdgcn_global_load_lds(                                    \
      (const __attribute__((address_space(1))) void*)(gp),             \
      (__attribute__((address_space(3))) void*)(lp), 16, 0, 0)

template <int N> __device__ __forceinline__ void vmwait() {
  if constexpr (N == 0)      asm volatile("s_waitcnt vmcnt(0)" ::: "memory");
  else if constexpr (N == 6) asm volatile("s_waitcnt vmcnt(6)" ::: "memory");
}

#define BAR()                                                          \
  { asm volatile("" ::: "memory");                                     \
    __builtin_amdgcn_s_barrier();                                      \
    asm volatile("" ::: "memory"); }

#define LGKM0() asm volatile("s_waitcnt lgkmcnt(0)" ::: "memory")

// ---------------------------------------------------------------------------
// Batched transpose + fp32->bf16 convert for four 1024x1024 weights.
// ---------------------------------------------------------------------------
struct TP4 { const float* s[4]; bf16* d[4]; };

__global__ __launch_bounds__(256) void transpose_conv4(TP4 p)
{
  __shared__ float tile[32][33];
  const float* __restrict__ src = p.s[blockIdx.z];
  bf16* __restrict__ dst = p.d[blockIdx.z];
  int n0 = blockIdx.x * 32, k0 = blockIdx.y * 32;
  int tx = threadIdx.x & 31, ty = threadIdx.x >> 5;
#pragma unroll
  for (int i = 0; i < 32; i += 8)
    tile[ty + i][tx] = src[(size_t)(k0 + ty + i) * 1024 + n0 + tx];
  __syncthreads();
#pragma unroll
  for (int i = 0; i < 32; i += 8)
    dst[(size_t)(n0 + ty + i) * 1024 + k0 + tx] = (bf16)tile[tx][ty + i];
}

__global__ __launch_bounds__(256) void transpose_conv(
    const float* __restrict__ src, bf16* __restrict__ dst, int K, int N)
{
  __shared__ float tile[32][33];
  int n0 = blockIdx.x * 32, k0 = blockIdx.y * 32;
  int tx = threadIdx.x & 31, ty = threadIdx.x >> 5;
#pragma unroll
  for (int i = 0; i < 32; i += 8)
    tile[ty + i][tx] = src[(size_t)(k0 + ty + i) * N + n0 + tx];
  __syncthreads();
#pragma unroll
  for (int i = 0; i < 32; i += 8)
    dst[(size_t)(n0 + ty + i) * K + k0 + tx] = (bf16)tile[tx][ty + i];
}

// ---------------------------------------------------------------------------
// cmod = silu(c) @ w_ada + b_ada      c:[8][1024]  w_ada:[1024][6144]
// ---------------------------------------------------------------------------
__global__ __launch_bounds__(256) void ada_kernel(
    const float* __restrict__ c, const float* __restrict__ w_ada,
    const float* __restrict__ b_ada, float* __restrict__ cmod)
{
  __shared__ float cs[1024];
  int b = blockIdx.y;
  int col = blockIdx.x * 256 + threadIdx.x;
  for (int i = threadIdx.x; i < 1024; i += 256) {
    float cv = c[b * 1024 + i];
    cs[i] = cv / (1.0f + __expf(-cv));
  }
  __syncthreads();
  float acc = b_ada[col];
#pragma unroll 8
  for (int kk = 0; kk < 1024; kk++)
    acc += cs[kk] * w_ada[(size_t)kk * CMS + col];
  cmod[b * CMS + col] = acc;
}

// ---------------------------------------------------------------------------
// LayerNorm (no affine) + modulate -> bf16.  One block per row.
// ---------------------------------------------------------------------------
__global__ __launch_bounds__(256) void ln_mod(
    const float* __restrict__ x, const float* __restrict__ cmod,
    bf16* __restrict__ out, int sh_off, int sc_off)
{
  int row = blockIdx.x, b = row >> 10, tid = threadIdx.x;
  const float4* xr = (const float4*)(x + (size_t)row * NHID);
  float4 v = xr[tid];
  float s  = v.x + v.y + v.z + v.w;
  float s2 = v.x * v.x + v.y * v.y + v.z * v.z + v.w * v.w;
#pragma unroll
  for (int off = 32; off; off >>= 1) {
    s  += __shfl_xor(s, off);
    s2 += __shfl_xor(s2, off);
  }
  __shared__ float red1[4], red2[4];
  int wave = tid >> 6, lane = tid & 63;
  if (lane == 0) { red1[wave] = s; red2[wave] = s2; }
  __syncthreads();
  float S  = red1[0] + red1[1] + red1[2] + red1[3];
  float S2 = red2[0] + red2[1] + red2[2] + red2[3];
  float mean = S * (1.0f / NHID);
  float var  = S2 * (1.0f / NHID) - mean * mean;
  float rs   = rsqrtf(var + 1e-6f);
  const float4* shp = (const float4*)(cmod + b * CMS + sh_off);
  const float4* scp = (const float4*)(cmod + b * CMS + sc_off);
  float4 sh4 = shp[tid], sc4 = scp[tid];
  bf16x4 o4;
  o4[0] = (bf16)((v.x - mean) * rs * (1.0f + sc4.x) + sh4.x);
  o4[1] = (bf16)((v.y - mean) * rs * (1.0f + sc4.y) + sh4.y);
  o4[2] = (bf16)((v.z - mean) * rs * (1.0f + sc4.z) + sh4.z);
  o4[3] = (bf16)((v.w - mean) * rs * (1.0f + sc4.w) + sh4.w);
  *(bf16x4*)(out + (size_t)row * NHID + tid * 4) = o4;
}

// ---------------------------------------------------------------------------
// 256x128-tile GEMM, 2 slots/tile, 2-deep LDS pipeline (R14). 96KB LDS.
// C[M][N] = A[M][K](bf16) @ Bt[N][K]^T + bias, fused epilogues.
// 8 waves 4Mx2N (per-wave 64x64). BK=64.
// LDS: A = 2buf x 2half(128 rows x 64k, 16KB) @0 (64KB);
//      B = 2buf x 2half(64 rows, 8KB) @65536 (32KB).
// XOR swizzle: 16B slot s of row r holds k-chunk s^(r&7) (pre-swizzled
// global source, linear GLD16 dest).
// Per tile t (buf p = t&1):
//  slot1: RDA(p,0) RDB(p,0) RDB(p,1); lgkm0; MM(0,0) MM(0,1)
//  slot2: RDA(p,1); lgkm0; BAR (all waves' reads of p done);
//         stage tile t+2 -> buf p (6 loads); vmcnt(6) (t+1 landed,
//         staged a full tile ago); BAR; MM(1,1) MM(1,0)
// Grid: 1D GX*32; xcd=bid&7 owns by in [xcd*4,xcd*4+4), bx sweeps.
// EPI: 1/3 = fp32 out = resid + gate*val; 2 = bf16 tanh-gelu;
//      5 = fused QKV (col<1024 q, <2048 k, else v transposed).
// ---------------------------------------------------------------------------
template <int EPI>
__global__ __launch_bounds__(512, 2) void gemm8(
    const bf16* __restrict__ A, const bf16* __restrict__ Bt,
    const float* __restrict__ bias, const float* __restrict__ bias2,
    const float* __restrict__ bias3,
    bf16* __restrict__ outb, bf16* __restrict__ outb2,
    bf16* __restrict__ outb3, float* __restrict__ outf,
    const float* __restrict__ cmod, int gate_off,
    const float* __restrict__ resid,
    int N, int K)
{
  constexpr int BOFF = 65536;          // LDS offset of B region

  extern __shared__ __align__(16) char smem[];

  const int tid  = threadIdx.x;
  // ---- XCD supertile decode: xcd owns 4 consecutive by rows, all bx ----
  const int xcd  = blockIdx.x & 7;
  const int slot = blockIdx.x >> 3;
  const int by   = xcd * 4 + (slot & 3);
  const int bx   = slot >> 2;
  const int bm = by * 256, bn = bx * 128;

  const int wave = tid >> 6, lane = tid & 63;
  const int wr = wave >> 1, wc = wave & 1;
  const int l16 = lane & 15, q4 = lane >> 4;

  // staging: thread -> (row rq [+64 for A], 16B slot tid&7), chunk pre-XOR'd
  const int rq = tid >> 3;
  const int ch = ((tid & 7) ^ (rq & 7)) * 8;
  const int wbase = (tid & 448) * 16;          // wave-uniform LDS base

  // ds_read bases (row&7 == l16&7; row offsets are multiples of 16/32)
  const int aRowB = (wr * 32 + l16) * 128;
  const int bRowB = (wc * 32 + l16) * 128;
  const int slotB = (q4 ^ (l16 & 7)) * 16;

  f32x4 acc[2][2][2][2];
#pragma unroll
  for (int a0 = 0; a0 < 2; a0++)
#pragma unroll
    for (int a1 = 0; a1 < 2; a1++)
#pragma unroll
      for (int a2 = 0; a2 < 2; a2++)
#pragma unroll
        for (int a3 = 0; a3 < 2; a3++) acc[a0][a1][a2][a3] = (f32x4)0.0f;

  auto stA = [&](int p, int half, int T) {
    const bf16* g = A + (size_t)(bm + half * 128 + rq) * K + T * 64 + ch;
    char* l = smem + p * 32768 + half * 16384 + wbase;
    GLD16(g, l);
    GLD16(g + (size_t)64 * K, l + 8192);
  };
  auto stB = [&](int p, int half, int T) {
    const bf16* g = Bt + (size_t)(bn + half * 64 + rq) * K + T * 64 + ch;
    char* l = smem + BOFF + p * 16384 + half * 8192 + wbase;
    GLD16(g, l);
  };

#define RDA(P, QM, FR)                                                     \
  { const char* ab_ = smem + (P) * 32768 + (QM) * 16384 + aRowB;           \
    _Pragma("unroll")                                                      \
    for (int ks = 0; ks < 2; ks++) {                                       \
      const int sb_ = slotB ^ (ks * 64);                                   \
      _Pragma("unroll")                                                    \
      for (int mf = 0; mf < 2; mf++)                                       \
        FR[ks][mf] = *(const bf16x8*)(ab_ + mf * 2048 + sb_);              \
    } }

#define RDB(P, QN, FR)                                                     \
  { const char* bb_ = smem + BOFF + (P) * 16384 + (QN) * 8192 + bRowB;     \
    _Pragma("unroll")                                                      \
    for (int ks = 0; ks < 2; ks++) {                                       \
      const int sb_ = slotB ^ (ks * 64);                                   \
      _Pragma("unroll")                                                    \
      for (int nf = 0; nf < 2; nf++)                                       \
        FR[ks][nf] = *(const bf16x8*)(bb_ + nf * 2048 + sb_);              \
    } }

#define MM(QM, QN, AF, BF)                                                 \
  { __builtin_amdgcn_s_setprio(1);                                         \
    _Pragma("unroll")                                                      \
    for (int mf = 0; mf < 2; mf++)                                         \
      _Pragma("unroll")                                                    \
      for (int nf = 0; nf < 2; nf++) {                                     \
        acc[QM][QN][mf][nf] = __builtin_amdgcn_mfma_f32_16x16x32_bf16(     \
            AF[0][mf], BF[0][nf], acc[QM][QN][mf][nf], 0, 0, 0);           \
        acc[QM][QN][mf][nf] = __builtin_amdgcn_mfma_f32_16x16x32_bf16(     \
            AF[1][mf], BF[1][nf], acc[QM][QN][mf][nf], 0, 0, 0);           \
      }                                                                    \
    __builtin_amdgcn_s_setprio(0); }

  const int NT = K >> 6;

  bf16x8 afr[2][2], bfr0[2][2], bfr1[2][2];

  // prologue: tile0 -> buf0, tile1 -> buf1 (6 loads each)
  stA(0, 0, 0); stB(0, 0, 0); stB(0, 1, 0); stA(0, 1, 0);
  stA(1, 0, 1); stB(1, 0, 1); stB(1, 1, 1); stA(1, 1, 1);
  vmwait<6>();        // tile0 landed; tile1's 6 stay in flight
  BAR();

  for (int t = 0; t < NT; ++t) {
    const int p = t & 1;
    const int T = (t + 2 < NT) ? t + 2 : t;   // clamp: dead restage, L2-hot
    // ---- slot1: A0,B0,B1 reads of buf p; first half of MFMAs
    RDA(p, 0, afr); RDB(p, 0, bfr0); RDB(p, 1, bfr1);
    LGKM0();
    MM(0, 0, afr, bfr0); MM(0, 1, afr, bfr1);
    // ---- slot2: A1 read; then restage p with tile t+2; gate tile t+1
    RDA(p, 1, afr);
    LGKM0();
    BAR();              // all waves' reads of buf p complete
    stA(p, 0, T); stB(p, 0, T); stB(p, 1, T); stA(p, 1, T);
    vmwait<6>();        // tile t+1's 6 landed (t+2's 6 outstanding)
    BAR();
    MM(1, 1, afr, bfr1); MM(1, 0, afr, bfr0);
  }
  vmwait<0>();
#undef RDA
#undef RDB
#undef MM

  // ---- epilogue ----
  const int colBase = bn + wc * 32 + l16;
  const int rowBase = bm + wr * 32 + q4 * 4;
#pragma unroll
  for (int qm = 0; qm < 2; qm++)
#pragma unroll
  for (int qn = 0; qn < 2; qn++)
#pragma unroll
  for (int mf = 0; mf < 2; mf++)
#pragma unroll
  for (int nf = 0; nf < 2; nf++) {
    const int col  = colBase + qn * 64 + nf * 16;
    const int row0 = rowBase + qm * 128 + mf * 16;
    f32x4 v = acc[qm][qn][mf][nf];
    if constexpr (EPI == 5) {
      const int sel = bn >> 10;          // block-uniform (128-aligned)
      const float* bp = (sel == 0) ? bias : (sel == 1) ? bias2 : bias3;
      const int colq = col & 1023;
      const float bcol = bp[colq];
      if (sel == 2) {
        // V: transposed write vt[b][hid][seq]; 4 consecutive seq rows
        bf16x4 o4;
#pragma unroll
        for (int r = 0; r < 4; r++) o4[r] = (bf16)(v[r] + bcol);
        const int bidx = row0 >> 10;
        *(bf16x4*)(outb3 + ((size_t)bidx * NHID + colq) * SEQ +
                   (row0 & 1023)) = o4;
      } else {
        bf16* qk = (sel == 0) ? outb : outb2;
#pragma unroll
        for (int r = 0; r < 4; r++)
          qk[(size_t)(row0 + r) * 1024 + colq] = (bf16)(v[r] + bcol);
      }
    } else if constexpr (EPI == 2) {
      const float bcol = bias[col];
#pragma unroll
      for (int r = 0; r < 4; r++) {
        float val = v[r] + bcol;
        float u2g = 2.0f * val * (0.7978845608f + 0.0356774081f * val * val);
        float e = __expf(u2g);
        float th = 1.0f - 2.0f / (e + 1.0f);
        outb[(size_t)(row0 + r) * N + col] = (bf16)(0.5f * val * (1.0f + th));
      }
    } else {  // EPI 1 / 3: fp32 out = resid + gate*val
      const float bcol = bias[col];
#pragma unroll
      for (int r = 0; r < 4; r++) {
        const int row = row0 + r;
        const float gg = cmod[(row >> 10) * CMS + gate_off + col];
        outf[(size_t)row * N + col] =
            resid[(size_t)row * N + col] + gg * (v[r] + bcol);
      }
    }
  }
}

// ---------------------------------------------------------------------------
// MFMA flash attention (R12 8-wave version — passing, kept).
// 512 blocks (4 qt x 16 h x 8 b), 512 threads, 256 q-rows per block.
// LDS: Ks 8KB + Vs 8KB + Ps 36KB = 52KB -> 2 blocks/CU.
// ---------------------------------------------------------------------------
__global__ __launch_bounds__(512) void attn_mfma(
    const bf16* __restrict__ q, const bf16* __restrict__ k,
    const bf16* __restrict__ vt, bf16* __restrict__ o)
{
  __shared__ __align__(16) bf16 Ks[64 * 64];
  __shared__ __align__(16) bf16 Vs[64 * 64];
  __shared__ __align__(16) bf16 Ps[8][32 * 72];   // [wave][qloc][key] stride 72

  int bid = blockIdx.x;
  int qt = bid & 3, h = (bid >> 2) & 15, b = bid >> 6;
  int tid = threadIdx.x, wave = tid >> 6, lane = tid & 63;
  int quad = lane >> 4, l16 = lane & 15;
  int qbase = qt * 256 + wave * 32;

  bf16x8 qf[2][2];
  const bf16* qp = q + ((size_t)(b * SEQ + qbase)) * NHID + h * HDIM;
#pragma unroll
  for (int nt = 0; nt < 2; nt++)
#pragma unroll
    for (int kk = 0; kk < 2; kk++) {
      bf16x8 t = *(const bf16x8*)(qp + (size_t)(nt * 16 + l16) * NHID +
                                  kk * 32 + quad * 8);
#pragma unroll
      for (int j = 0; j < 8; j++) t[j] = (bf16)((float)t[j] * 0.015625f);
      qf[nt][kk] = t;
    }

  f32x4 oacc[4][2];
#pragma unroll
  for (int mt = 0; mt < 4; mt++)
#pragma unroll
    for (int nt = 0; nt < 2; nt++) oacc[mt][nt] = (f32x4)0.0f;
  float m_[2] = {-3.0e38f, -3.0e38f}, l_[2] = {0.0f, 0.0f};

  const bf16* kb = k + ((size_t)(b * SEQ)) * NHID + h * HDIM;
  const bf16* vb = vt + ((size_t)(b * NHID + h * HDIM)) * SEQ;

  // 512-thread staging: rq in [0,64), one GLD16 per matrix per thread
  const int sr0 = tid >> 3, sc0 = tid & 7;
  const int cg0 = (sc0 ^ (sr0 & 7)) * 8;
  bf16* lk0 = Ks + (size_t)(tid & 448) * 8;   // wave-uniform base
  bf16* lv0 = Vs + (size_t)(tid & 448) * 8;

  for (int kt = 0; kt < 16; kt++) {
    __syncthreads();   // prior-iter K/V LDS reads done before restage
    GLD16(kb + (size_t)(kt * 64 + sr0) * NHID + cg0, lk0);
    GLD16(vb + (size_t)sr0 * SEQ + kt * 64 + cg0, lv0);
    __syncthreads();

    // ---- S^T = K @ Q^T  (already scaled via qf)
    f32x4 sacc[4][2];
#pragma unroll
    for (int mt = 0; mt < 4; mt++)
#pragma unroll
      for (int nt = 0; nt < 2; nt++) sacc[mt][nt] = (f32x4)0.0f;
#pragma unroll
    for (int kk = 0; kk < 2; kk++) {
      bf16x8 kf[4];
#pragma unroll
      for (int mt = 0; mt < 4; mt++) {
        int row = mt * 16 + l16;
        kf[mt] = *(const bf16x8*)(Ks + row * 64 +
                                  (((kk * 4 + quad) ^ (row & 7)) * 8));
      }
#pragma unroll
      for (int mt = 0; mt < 4; mt++)
#pragma unroll
        for (int nt = 0; nt < 2; nt++)
          sacc[mt][nt] = __builtin_amdgcn_mfma_f32_16x16x32_bf16(
              kf[mt], qf[nt][kk], sacc[mt][nt], 0, 0, 0);
    }

    // ---- online softmax (per q column = per (nt, l16))
    float alpha[2];
#pragma unroll
    for (int nt = 0; nt < 2; nt++) {
      float tm = -3.0e38f;
#pragma unroll
      for (int mt = 0; mt < 4; mt++)
#pragma unroll
        for (int r = 0; r < 4; r++) tm = fmaxf(tm, sacc[mt][nt][r]);
      tm = fmaxf(tm, __shfl_xor(tm, 16));
      tm = fmaxf(tm, __shfl_xor(tm, 32));
      float mn = fmaxf(m_[nt], tm);
      alpha[nt] = __expf(m_[nt] - mn);
      m_[nt] = mn;
      float ts = 0.0f;
#pragma unroll
      for (int mt = 0; mt < 4; mt++) {
        bf16x4 pv;
#pragma unroll
        for (int r = 0; r < 4; r++) {
          float p = __expf(sacc[mt][nt][r] - mn);
          ts += p;
          pv[r] = (bf16)p;
        }
        *(bf16x4*)(&Ps[wave][(nt * 16 + l16) * 72 + mt * 16 + quad * 4]) = pv;
      }
      ts += __shfl_xor(ts, 16);
      ts += __shfl_xor(ts, 32);
      l_[nt] = l_[nt] * alpha[nt] + ts;
    }
#pragma unroll
    for (int mt = 0; mt < 4; mt++)
#pragma unroll
      for (int nt = 0; nt < 2; nt++)
#pragma unroll
        for (int r = 0; r < 4; r++) oacc[mt][nt][r] *= alpha[nt];

    // Wave-level fence: Ps is wave-private (R2/R5 post-mortems).
    __asm__ volatile("s_waitcnt lgkmcnt(0)" ::: "memory");

    // ---- O^T += V^T @ P^T
#pragma unroll
    for (int kk = 0; kk < 2; kk++) {
      bf16x8 vf[4], pf[2];
#pragma unroll
      for (int mt = 0; mt < 4; mt++) {
        int row = mt * 16 + l16;
        vf[mt] = *(const bf16x8*)(Vs + row * 64 +
                                  (((kk * 4 + quad) ^ (row & 7)) * 8));
      }
#pragma unroll
      for (int nt = 0; nt < 2; nt++)
        pf[nt] = *(const bf16x8*)(&Ps[wave][(nt * 16 + l16) * 72 +
                                            kk * 32 + quad * 8]);
#pragma unroll
      for (int mt = 0; mt < 4; mt++)
#pragma unroll
        for (int nt = 0; nt < 2; nt++)
          oacc[mt][nt] = __builtin_amdgcn_mfma_f32_16x16x32_bf16(
              vf[mt], pf[nt], oacc[mt][nt], 0, 0, 0);
    }
  }

  // ---- write O (un-transposing: per lane 4 consecutive hid cols)
#pragma unroll
  for (int nt = 0; nt < 2; nt++) {
    float rl = 1.0f / l_[nt];
#pragma unroll
    for (int mt = 0; mt < 4; mt++) {
      bf16x4 o4;
#pragma unroll
      for (int r = 0; r < 4; r++) o4[r] = (bf16)(oacc[mt][nt][r] * rl);
      *(bf16x4*)(o + ((size_t)(b * SEQ + qbase + nt * 16 + l16)) * NHID +
                 h * HDIM + mt * 16 + quad * 4) = o4;
    }
  }
}

// ---------------------------------------------------------------------------
// Workspace layout (bytes). Total ~136.2 MiB.
// wqT/wkT/wvT contiguous -> one [3072][1024] QKV weight matrix.
// ---------------------------------------------------------------------------
#define OFF_CMOD 0u
#define OFF_WQT  196608u
#define OFF_WKT  (OFF_WQT + 2097152u)
#define OFF_WVT  (OFF_WKT + 2097152u)
#define OFF_WOT  (OFF_WVT + 2097152u)
#define OFF_W1T  (OFF_WOT + 2097152u)
#define OFF_W2T  (OFF_W1T + 8388608u)
#define OFF_X2   (OFF_W2T + 8388608u)
#define OFF_XM2  (OFF_X2  + 33554432u)
#define OFF_POOL (OFF_XM2 + 16777216u)
// pool (67.1 MB): xm @ +0, q @ +16M, k @ +32M, vt @ +48M.
// o aliases xm (dead after QKV GEMM); h aliases whole pool.

extern "C" void kernel_launch(void* const* d_in, const int* in_sizes, int n_in,
                              void* d_out, int out_size, void* d_ws, size_t ws_size,
                              hipStream_t stream)
{
  const float* x     = (const float*)d_in[0];
  const float* c     = (const float*)d_in[1];
  const float* w_ada = (const float*)d_in[2];
  const float* b_ada = (const float*)d_in[3];
  const float* wq = (const float*)d_in[4];  const float* bq = (const float*)d_in[5];
  const float* wk = (const float*)d_in[6];  const float* bk = (const float*)d_in[7];
  const float* wv = (const float*)d_in[8];  const float* bv = (const float*)d_in[9];
  const float* wo = (const float*)d_in[10]; const float* bo = (const float*)d_in[11];
  const float* w1 = (const float*)d_in[12]; const float* b1 = (const float*)d_in[13];
  const float* w2 = (const float*)d_in[14]; const float* b2 = (const float*)d_in[15];
  float* out = (float*)d_out;
  char* ws = (char*)d_ws;

  float* cmod = (float*)(ws + OFF_CMOD);
  bf16* wqT = (bf16*)(ws + OFF_WQT);     // base of contiguous [3072][1024]
  bf16* wkT = (bf16*)(ws + OFF_WKT);
  bf16* wvT = (bf16*)(ws + OFF_WVT);
  bf16* woT = (bf16*)(ws + OFF_WOT);
  bf16* w1T = (bf16*)(ws + OFF_W1T);
  bf16* w2T = (bf16*)(ws + OFF_W2T);
  float* x2 = (float*)(ws + OFF_X2);
  bf16* xm2 = (bf16*)(ws + OFF_XM2);
  bf16* xm  = (bf16*)(ws + OFF_POOL);
  bf16* qb  = (bf16*)(ws + OFF_POOL + 16777216u);
  bf16* kb  = (bf16*)(ws + OFF_POOL + 33554432u);
  bf16* vtb = (bf16*)(ws + OFF_POOL + 50331648u);
  bf16* ob  = xm;   // alias
  bf16* hb  = xm;   // alias (covers 64 MB of pool)

  static bool attr_set = false;
  if (!attr_set) {
    hipFuncSetAttribute(reinterpret_cast<const void*>(&gemm8<5>),
                        hipFuncAttributeMaxDynamicSharedMemorySize, 98304);
    hipFuncSetAttribute(reinterpret_cast<const void*>(&gemm8<1>),
                        hipFuncAttributeMaxDynamicSharedMemorySize, 98304);
    hipFuncSetAttribute(reinterpret_cast<const void*>(&gemm8<2>),
                        hipFuncAttributeMaxDynamicSharedMemorySize, 98304);
    hipFuncSetAttribute(reinterpret_cast<const void*>(&gemm8<3>),
                        hipFuncAttributeMaxDynamicSharedMemorySize, 98304);
    attr_set = true;
  }

  TP4 tp;
  tp.s[0] = wq; tp.s[1] = wk; tp.s[2] = wv; tp.s[3] = wo;
  tp.d[0] = wqT; tp.d[1] = wkT; tp.d[2] = wvT; tp.d[3] = woT;
  transpose_conv4<<<dim3(32, 32, 4), 256, 0, stream>>>(tp);
  transpose_conv<<<dim3(128, 32), 256, 0, stream>>>(w1, w1T, 1024, 4096);
  transpose_conv<<<dim3(32, 128), 256, 0, stream>>>(w2, w2T, 4096, 1024);

  ada_kernel<<<dim3(24, 8), 256, 0, stream>>>(c, w_ada, b_ada, cmod);

  // ln1 + modulate (sh_msa @ 0, sc_msa @ 1024)
  ln_mod<<<8192, 256, 0, stream>>>(x, cmod, xm, 0, 1024);

  // fused QKV: N=3072; q/k normal, v transposed (vt[b][hid][seq])
  // grid = GX*32 1D, GX = 24
  gemm8<5><<<768, 512, 98304, stream>>>(
      xm, wqT, bq, bk, bv, qb, kb, vtb, nullptr, nullptr, 0, nullptr,
      1024, 1024);

  // attention: 512 blocks (4 qt x 16 h x 8 b), 512 threads
  attn_mfma<<<512, 512, 0, stream>>>(qb, kb, vtb, ob);

  // x2 = x + g_msa * (o @ wo + bo)      (g_msa @ 2048)  GX = 8
  gemm8<1><<<256, 512, 98304, stream>>>(
      ob, woT, bo, nullptr, nullptr, nullptr, nullptr, nullptr, x2,
      cmod, 2048, x, 1024, 1024);

  // ln2 + modulate (sh_mlp @ 3072, sc_mlp @ 4096)
  ln_mod<<<8192, 256, 0, stream>>>(x2, cmod, xm2, 3072, 4096);

  // h = gelu(xm2 @ w1 + b1)   (tanh form)  GX = 32
  gemm8<2><<<1024, 512, 98304, stream>>>(
      xm2, w1T, b1, nullptr, nullptr, hb, nullptr, nullptr, nullptr,
      nullptr, 0, nullptr, 4096, 1024);

  // out = x2 + g_mlp * (h @ w2 + b2)    (g_mlp @ 5120)  GX = 8
  gemm8<3><<<256, 512, 98304, stream>>>(
      hb, w2T, b2, nullptr, nullptr, nullptr, nullptr, nullptr, out,
      cmod, 5120, x2, 1024, 4096);
}

// Round 9
// 503.130 us; speedup vs baseline: 1.0953x; 1.0953x over previous
//
#include <hip/hip_runtime.h>
#include <hip/hip_bf16.h>
#include <cstdint>

// DiT block: B=8, N=1024, HID=1024, NH=16, HD=64, MLP=4096.
// R15: GEMMs reverted to R12 exactly (best: 542.6 us; 7 schedule variants
// all ~700-770 TF -> GEMM schedule declared exhausted at source level for
// these rectangular shapes). Two non-GEMM changes:
// (1) attention K/V double-buffer: stage kt+1 during kt's compute, ONE
//     __syncthreads per kt (implicit vmcnt0 drain is the gate). LDS 68KB,
//     still 2 blocks/CU. Removes exposed stage latency + 1 barrier/kt.
// (2) ada k-split x4 (grid 24x8x4, 256-iter loop, atomicAdd fp32 into
//     hipMemsetAsync-zeroed cmod): latency-bound 1024-chain -> 256.

typedef __bf16 bf16;
typedef __attribute__((ext_vector_type(8))) __bf16 bf16x8;
typedef __attribute__((ext_vector_type(4))) __bf16 bf16x4;
typedef __attribute__((ext_vector_type(4))) float f32x4;

#define SEQ   1024
#define NHID  1024
#define NHEAD 16
#define HDIM  64
#define CMS   6144          // cmod row stride

// async 16B global->LDS: lds dest = wave-uniform base + lane*16
#define GLD16(gp, lp)                                                  \
  __builtin_amdgcn_global_load_lds(                                    \
      (const __attribute__((address_space(1))) void*)(gp),             \
      (__attribute__((address_space(3))) void*)(lp), 16, 0, 0)

template <int N> __device__ __forceinline__ void vmwait() {
  if constexpr (N == 0)      asm volatile("s_waitcnt vmcnt(0)" ::: "memory");
  else if constexpr (N == 4) asm volatile("s_waitcnt vmcnt(4)" ::: "memory");
  else if constexpr (N == 6) asm volatile("s_waitcnt vmcnt(6)" ::: "memory");
}

#define BAR()                                                          \
  { asm volatile("" ::: "memory");                                     \
    __builtin_amdgcn_s_barrier();                                      \
    asm volatile("" ::: "memory"); }

#define LGKM0() asm volatile("s_waitcnt lgkmcnt(0)" ::: "memory")

// ---------------------------------------------------------------------------
// Batched transpose + fp32->bf16 convert for four 1024x1024 weights.
// ---------------------------------------------------------------------------
struct TP4 { const float* s[4]; bf16* d[4]; };

__global__ __launch_bounds__(256) void transpose_conv4(TP4 p)
{
  __shared__ float tile[32][33];
  const float* __restrict__ src = p.s[blockIdx.z];
  bf16* __restrict__ dst = p.d[blockIdx.z];
  int n0 = blockIdx.x * 32, k0 = blockIdx.y * 32;
  int tx = threadIdx.x & 31, ty = threadIdx.x >> 5;
#pragma unroll
  for (int i = 0; i < 32; i += 8)
    tile[ty + i][tx] = src[(size_t)(k0 + ty + i) * 1024 + n0 + tx];
  __syncthreads();
#pragma unroll
  for (int i = 0; i < 32; i += 8)
    dst[(size_t)(n0 + ty + i) * 1024 + k0 + tx] = (bf16)tile[tx][ty + i];
}

__global__ __launch_bounds__(256) void transpose_conv(
    const float* __restrict__ src, bf16* __restrict__ dst, int K, int N)
{
  __shared__ float tile[32][33];
  int n0 = blockIdx.x * 32, k0 = blockIdx.y * 32;
  int tx = threadIdx.x & 31, ty = threadIdx.x >> 5;
#pragma unroll
  for (int i = 0; i < 32; i += 8)
    tile[ty + i][tx] = src[(size_t)(k0 + ty + i) * N + n0 + tx];
  __syncthreads();
#pragma unroll
  for (int i = 0; i < 32; i += 8)
    dst[(size_t)(n0 + ty + i) * K + k0 + tx] = (bf16)tile[tx][ty + i];
}

// ---------------------------------------------------------------------------
// cmod = silu(c) @ w_ada + b_ada      c:[8][1024]  w_ada:[1024][6144]
// R15: k-split x4, grid (24, 8, 4); cmod pre-zeroed; atomicAdd fp32.
// ---------------------------------------------------------------------------
__global__ __launch_bounds__(256) void ada_kernel(
    const float* __restrict__ c, const float* __restrict__ w_ada,
    const float* __restrict__ b_ada, float* __restrict__ cmod)
{
  __shared__ float cs[256];
  const int b  = blockIdx.y;
  const int k0 = blockIdx.z * 256;
  const int col = blockIdx.x * 256 + threadIdx.x;
  {
    float cv = c[b * 1024 + k0 + threadIdx.x];
    cs[threadIdx.x] = cv / (1.0f + __expf(-cv));
  }
  __syncthreads();
  float acc = (blockIdx.z == 0) ? b_ada[col] : 0.0f;
#pragma unroll 8
  for (int kk = 0; kk < 256; kk++)
    acc += cs[kk] * w_ada[(size_t)(k0 + kk) * CMS + col];
  atomicAdd(&cmod[b * CMS + col], acc);
}

// ---------------------------------------------------------------------------
// LayerNorm (no affine) + modulate -> bf16.  One block per row.
// ---------------------------------------------------------------------------
__global__ __launch_bounds__(256) void ln_mod(
    const float* __restrict__ x, const float* __restrict__ cmod,
    bf16* __restrict__ out, int sh_off, int sc_off)
{
  int row = blockIdx.x, b = row >> 10, tid = threadIdx.x;
  const float4* xr = (const float4*)(x + (size_t)row * NHID);
  float4 v = xr[tid];
  float s  = v.x + v.y + v.z + v.w;
  float s2 = v.x * v.x + v.y * v.y + v.z * v.z + v.w * v.w;
#pragma unroll
  for (int off = 32; off; off >>= 1) {
    s  += __shfl_xor(s, off);
    s2 += __shfl_xor(s2, off);
  }
  __shared__ float red1[4], red2[4];
  int wave = tid >> 6, lane = tid & 63;
  if (lane == 0) { red1[wave] = s; red2[wave] = s2; }
  __syncthreads();
  float S  = red1[0] + red1[1] + red1[2] + red1[3];
  float S2 = red2[0] + red2[1] + red2[2] + red2[3];
  float mean = S * (1.0f / NHID);
  float var  = S2 * (1.0f / NHID) - mean * mean;
  float rs   = rsqrtf(var + 1e-6f);
  const float4* shp = (const float4*)(cmod + b * CMS + sh_off);
  const float4* scp = (const float4*)(cmod + b * CMS + sc_off);
  float4 sh4 = shp[tid], sc4 = scp[tid];
  bf16x4 o4;
  o4[0] = (bf16)((v.x - mean) * rs * (1.0f + sc4.x) + sh4.x);
  o4[1] = (bf16)((v.y - mean) * rs * (1.0f + sc4.y) + sh4.y);
  o4[2] = (bf16)((v.z - mean) * rs * (1.0f + sc4.z) + sh4.z);
  o4[3] = (bf16)((v.w - mean) * rs * (1.0f + sc4.w) + sh4.w);
  *(bf16x4*)(out + (size_t)row * NHID + tid * 4) = o4;
}

// ---------------------------------------------------------------------------
// 8-phase 256-row GEMM, m201-ordered slots, register fragment reuse,
// XCD supertile swizzle (R10/R12 — unchanged). 1D grid of GX*32 blocks.
// xcd = bid&7 owns by in [xcd*4, xcd*4+4), bx sweeps 0..GX.
// 8 waves: BN=256 -> 2Mx4N (per-wave 128x64); BN=128 -> 4Mx2N (64x64).
// LDS: A = 2buf x 2half(128 rows) x 64k; B = 2buf x 2half(BN/2 rows) x 64k.
// XOR swizzle: 16B slot s of row r holds k-chunk s^(r&7).
// EPI: 1/3 = fp32 out = resid + gate*val; 2 = bf16 tanh-gelu;
//      5 = fused QKV (col<1024 q, <2048 k, else v transposed).
// ---------------------------------------------------------------------------
template <int EPI, int BN>
__global__ __launch_bounds__(512, 2) void gemm8(
    const bf16* __restrict__ A, const bf16* __restrict__ Bt,
    const float* __restrict__ bias, const float* __restrict__ bias2,
    const float* __restrict__ bias3,
    bf16* __restrict__ outb, bf16* __restrict__ outb2,
    bf16* __restrict__ outb3, float* __restrict__ outf,
    const float* __restrict__ cmod, int gate_off,
    const float* __restrict__ resid,
    int N, int K)
{
  constexpr int BNH   = BN / 2;        // rows per B half-region
  constexpr int LB    = BNH / 64;      // gld16 per thread per B half (2 or 1)
  constexpr int MF    = BN / 64;       // A m-frags per slot (4 or 2)
  constexpr int WC    = BN / 64;       // waves along N (4 or 2)
  constexpr int WRS   = 256 / (8 / WC) / 2;  // per-wave A row span (64 or 32)
  constexpr int VMN   = (LB == 2) ? 6 : 4;   // once-per-K-tile gate
  constexpr int BOFF  = 65536;         // LDS offset of B
  constexpr int BBUF  = BNH * 256;     // B bytes per buffer
  constexpr int BHALF = BNH * 128;     // B bytes per half-region

  extern __shared__ __align__(16) char smem[];

  const int tid  = threadIdx.x;
  // ---- XCD supertile decode: xcd owns 4 consecutive by rows, all bx ----
  const int xcd  = blockIdx.x & 7;
  const int slot = blockIdx.x >> 3;
  const int by   = xcd * 4 + (slot & 3);
  const int bx   = slot >> 2;
  const int bm = by * 256, bn = bx * BN;

  const int wave = tid >> 6, lane = tid & 63;
  const int wr = wave / WC, wc = wave % WC;
  const int l16 = lane & 15, q4 = lane >> 4;

  // staging: thread -> (row rq [+64], 16B slot tid&7), chunk pre-XOR'd
  const int rq = tid >> 3;
  const int ch = ((tid & 7) ^ (rq & 7)) * 8;
  const int wbase = (tid & 448) * 16;          // wave-uniform LDS base

  // ds_read bases: row&7 == l16&7 for all frags (row offsets mult of 16/32)
  const int aRowB = (wr * WRS + l16) * 128;
  const int bRowB = (wc * 32 + l16) * 128;
  const int slotB = (q4 ^ (l16 & 7)) * 16;

  f32x4 acc[2][2][MF][2];
#pragma unroll
  for (int a0 = 0; a0 < 2; a0++)
#pragma unroll
    for (int a1 = 0; a1 < 2; a1++)
#pragma unroll
      for (int a2 = 0; a2 < MF; a2++)
#pragma unroll
        for (int a3 = 0; a3 < 2; a3++) acc[a0][a1][a2][a3] = (f32x4)0.0f;

  auto stA = [&](int buf, int half, int T) {
    const bf16* g = A + (size_t)(bm + half * 128 + rq) * K + T * 64 + ch;
    char* l = smem + buf * 32768 + half * 16384 + wbase;
    GLD16(g, l);
    GLD16(g + (size_t)64 * K, l + 8192);
  };
  auto stB = [&](int buf, int half, int T) {
    const bf16* g = Bt + (size_t)(bn + half * BNH + rq) * K + T * 64 + ch;
    char* l = smem + BOFF + buf * BBUF + half * BHALF + wbase;
    GLD16(g, l);
    if constexpr (LB == 2) { GLD16(g + (size_t)64 * K, l + 8192); }
  };

#define RDA(BUF, QM, FR)                                                   \
  { const char* ab_ = smem + (BUF) * 32768 + (QM) * 16384 + aRowB;         \
    _Pragma("unroll")                                                      \
    for (int ks = 0; ks < 2; ks++) {                                       \
      const int sb_ = slotB ^ (ks * 64);                                   \
      _Pragma("unroll")                                                    \
      for (int mf = 0; mf < MF; mf++)                                      \
        FR[ks][mf] = *(const bf16x8*)(ab_ + mf * 2048 + sb_);              \
    } }

#define RDB(BUF, QN, FR)                                                   \
  { const char* bb_ = smem + BOFF + (BUF) * BBUF + (QN) * BHALF + bRowB;   \
    _Pragma("unroll")                                                      \
    for (int ks = 0; ks < 2; ks++) {                                       \
      const int sb_ = slotB ^ (ks * 64);                                   \
      _Pragma("unroll")                                                    \
      for (int nf = 0; nf < 2; nf++)                                       \
        FR[ks][nf] = *(const bf16x8*)(bb_ + nf * 2048 + sb_);              \
    } }

#define MM(QM, QN, AF, BF)                                                 \
  { __builtin_amdgcn_s_setprio(1);                                         \
    _Pragma("unroll")                                                      \
    for (int mf = 0; mf < MF; mf++)                                        \
      _Pragma("unroll")                                                    \
      for (int nf = 0; nf < 2; nf++) {                                     \
        acc[QM][QN][mf][nf] = __builtin_amdgcn_mfma_f32_16x16x32_bf16(     \
            AF[0][mf], BF[0][nf], acc[QM][QN][mf][nf], 0, 0, 0);           \
        acc[QM][QN][mf][nf] = __builtin_amdgcn_mfma_f32_16x16x32_bf16(     \
            AF[1][mf], BF[1][nf], acc[QM][QN][mf][nf], 0, 0, 0);           \
      }                                                                    \
    __builtin_amdgcn_s_setprio(0); }

  const int NT = K >> 6, NI = NT >> 1;

  bf16x8 afr[2][MF], bfr0[2][2], bfr1[2][2];

  // prologue: tile0 fully, tile1 all but A1 (A1(1) staged at s1 of tile 0)
  stA(0, 0, 0); stB(0, 0, 0); stB(0, 1, 0); stA(0, 1, 0);
  stA(1, 0, 1); stB(1, 0, 1); stB(1, 1, 1);
  vmwait<VMN>();
  BAR();

  for (int i = 0; i < NI; ++i) {
    const int t = 2 * i;
    const int u2 = (t + 2 < NT) ? t + 2 : NT - 2;  // clamp: dead, L2-hot
    const int u3 = (t + 3 < NT) ? t + 3 : NT - 1;
    // ---- tile t (buf0)
    RDA(0, 0, afr); RDB(0, 0, bfr0);
    stA(1, 1, t + 1);
    BAR(); LGKM0();
    MM(0, 0, afr, bfr0);
    BAR();
    RDB(0, 1, bfr1);
    stA(0, 0, u2);
    BAR(); LGKM0();
    MM(0, 1, afr, bfr1);
    BAR();
    RDA(0, 1, afr);
    stB(0, 0, u2);
    BAR(); LGKM0();
    MM(1, 1, afr, bfr1);
    BAR();
    stB(0, 1, u2);
    vmwait<VMN>();
    BAR();
    MM(1, 0, afr, bfr0);
    BAR();
    // ---- tile t+1 (buf1)
    RDA(1, 0, afr); RDB(1, 0, bfr0);
    stA(0, 1, u2);
    BAR(); LGKM0();
    MM(0, 0, afr, bfr0);
    BAR();
    RDB(1, 1, bfr1);
    stA(1, 0, u3);
    BAR(); LGKM0();
    MM(0, 1, afr, bfr1);
    BAR();
    RDA(1, 1, afr);
    stB(1, 0, u3);
    BAR(); LGKM0();
    MM(1, 1, afr, bfr1);
    BAR();
    stB(1, 1, u3);
    vmwait<VMN>();
    BAR();
    MM(1, 0, afr, bfr0);
    BAR();
  }
  vmwait<0>();
#undef RDA
#undef RDB
#undef MM

  // ---- epilogue ----
  const int colBase = bn + wc * 32 + l16;
  const int rowBase = bm + wr * WRS + q4 * 4;
#pragma unroll
  for (int qm = 0; qm < 2; qm++)
#pragma unroll
  for (int qn = 0; qn < 2; qn++)
#pragma unroll
  for (int mf = 0; mf < MF; mf++)
#pragma unroll
  for (int nf = 0; nf < 2; nf++) {
    const int col  = colBase + qn * BNH + nf * 16;
    const int row0 = rowBase + qm * 128 + mf * 16;
    f32x4 v = acc[qm][qn][mf][nf];
    if constexpr (EPI == 5) {
      const int sel = bn >> 10;          // block-uniform (BN<=256 aligned)
      const float* bp = (sel == 0) ? bias : (sel == 1) ? bias2 : bias3;
      const int colq = col & 1023;
      const float bcol = bp[colq];
      if (sel == 2) {
        // V: transposed write vt[b][hid][seq]; 4 consecutive seq rows
        bf16x4 o4;
#pragma unroll
        for (int r = 0; r < 4; r++) o4[r] = (bf16)(v[r] + bcol);
        const int bidx = row0 >> 10;
        *(bf16x4*)(outb3 + ((size_t)bidx * NHID + colq) * SEQ +
                   (row0 & 1023)) = o4;
      } else {
        bf16* qk = (sel == 0) ? outb : outb2;
#pragma unroll
        for (int r = 0; r < 4; r++)
          qk[(size_t)(row0 + r) * 1024 + colq] = (bf16)(v[r] + bcol);
      }
    } else if constexpr (EPI == 2) {
      const float bcol = bias[col];
#pragma unroll
      for (int r = 0; r < 4; r++) {
        float val = v[r] + bcol;
        float u2g = 2.0f * val * (0.7978845608f + 0.0356774081f * val * val);
        float e = __expf(u2g);
        float th = 1.0f - 2.0f / (e + 1.0f);
        outb[(size_t)(row0 + r) * N + col] = (bf16)(0.5f * val * (1.0f + th));
      }
    } else {  // EPI 1 / 3: fp32 out = resid + gate*val
      const float bcol = bias[col];
#pragma unroll
      for (int r = 0; r < 4; r++) {
        const int row = row0 + r;
        const float gg = cmod[(row >> 10) * CMS + gate_off + col];
        outf[(size_t)row * N + col] =
            resid[(size_t)row * N + col] + gg * (v[r] + bcol);
      }
    }
  }
}

// ---------------------------------------------------------------------------
// MFMA flash attention. R15: K/V double-buffered — stage kt+1 during kt's
// compute; ONE __syncthreads per kt (its implicit vmcnt(0) drain gates the
// next iteration's reads; the stage always targets the buffer not being
// read, and the previous barrier ordered that buffer's reads).
// 512 blocks (4 qt x 16 h x 8 b), 512 threads, 256 q-rows per block.
// LDS: Ks 16KB + Vs 16KB + Ps 36KB = 68KB -> 2 blocks/CU.
// ---------------------------------------------------------------------------
__global__ __launch_bounds__(512) void attn_mfma(
    const bf16* __restrict__ q, const bf16* __restrict__ k,
    const bf16* __restrict__ vt, bf16* __restrict__ o)
{
  __shared__ __align__(16) bf16 Ks[2][64 * 64];
  __shared__ __align__(16) bf16 Vs[2][64 * 64];
  __shared__ __align__(16) bf16 Ps[8][32 * 72];   // [wave][qloc][key] stride 72

  int bid = blockIdx.x;
  int qt = bid & 3, h = (bid >> 2) & 15, b = bid >> 6;
  int tid = threadIdx.x, wave = tid >> 6, lane = tid & 63;
  int quad = lane >> 4, l16 = lane & 15;
  int qbase = qt * 256 + wave * 32;

  bf16x8 qf[2][2];
  const bf16* qp = q + ((size_t)(b * SEQ + qbase)) * NHID + h * HDIM;
#pragma unroll
  for (int nt = 0; nt < 2; nt++)
#pragma unroll
    for (int kk = 0; kk < 2; kk++) {
      bf16x8 t = *(const bf16x8*)(qp + (size_t)(nt * 16 + l16) * NHID +
                                  kk * 32 + quad * 8);
#pragma unroll
      for (int j = 0; j < 8; j++) t[j] = (bf16)((float)t[j] * 0.015625f);
      qf[nt][kk] = t;
    }

  f32x4 oacc[4][2];
#pragma unroll
  for (int mt = 0; mt < 4; mt++)
#pragma unroll
    for (int nt = 0; nt < 2; nt++) oacc[mt][nt] = (f32x4)0.0f;
  float m_[2] = {-3.0e38f, -3.0e38f}, l_[2] = {0.0f, 0.0f};

  const bf16* kb = k + ((size_t)(b * SEQ)) * NHID + h * HDIM;
  const bf16* vb = vt + ((size_t)(b * NHID + h * HDIM)) * SEQ;

  // 512-thread staging: rq in [0,64), one GLD16 per matrix per thread
  const int sr0 = tid >> 3, sc0 = tid & 7;
  const int cg0 = (sc0 ^ (sr0 & 7)) * 8;
  const int lofs = (tid & 448) * 8;           // wave-uniform element base

  auto stage = [&](int p, int kt) {
    GLD16(kb + (size_t)(kt * 64 + sr0) * NHID + cg0, &Ks[p][0] + lofs);
    GLD16(vb + (size_t)sr0 * SEQ + kt * 64 + cg0, &Vs[p][0] + lofs);
  };

  stage(0, 0);
  __syncthreads();      // implicit vmcnt(0): buf0 ready

  for (int kt = 0; kt < 16; kt++) {
    const int p = kt & 1;
    if (kt + 1 < 16) stage(p ^ 1, kt + 1);

    // ---- S^T = K @ Q^T  (already scaled via qf)
    f32x4 sacc[4][2];
#pragma unroll
    for (int mt = 0; mt < 4; mt++)
#pragma unroll
      for (int nt = 0; nt < 2; nt++) sacc[mt][nt] = (f32x4)0.0f;
#pragma unroll
    for (int kk = 0; kk < 2; kk++) {
      bf16x8 kf[4];
#pragma unroll
      for (int mt = 0; mt < 4; mt++) {
        int row = mt * 16 + l16;
        kf[mt] = *(const bf16x8*)(&Ks[p][0] + row * 64 +
                                  (((kk * 4 + quad) ^ (row & 7)) * 8));
      }
#pragma unroll
      for (int mt = 0; mt < 4; mt++)
#pragma unroll
        for (int nt = 0; nt < 2; nt++)
          sacc[mt][nt] = __builtin_amdgcn_mfma_f32_16x16x32_bf16(
              kf[mt], qf[nt][kk], sacc[mt][nt], 0, 0, 0);
    }

    // ---- online softmax (per q column = per (nt, l16))
    float alpha[2];
#pragma unroll
    for (int nt = 0; nt < 2; nt++) {
      float tm = -3.0e38f;
#pragma unroll
      for (int mt = 0; mt < 4; mt++)
#pragma unroll
        for (int r = 0; r < 4; r++) tm = fmaxf(tm, sacc[mt][nt][r]);
      tm = fmaxf(tm, __shfl_xor(tm, 16));
      tm = fmaxf(tm, __shfl_xor(tm, 32));
      float mn = fmaxf(m_[nt], tm);
      alpha[nt] = __expf(m_[nt] - mn);
      m_[nt] = mn;
      float ts = 0.0f;
#pragma unroll
      for (int mt = 0; mt < 4; mt++) {
        bf16x4 pv;
#pragma unroll
        for (int r = 0; r < 4; r++) {
          float p2 = __expf(sacc[mt][nt][r] - mn);
          ts += p2;
          pv[r] = (bf16)p2;
        }
        *(bf16x4*)(&Ps[wave][(nt * 16 + l16) * 72 + mt * 16 + quad * 4]) = pv;
      }
      ts += __shfl_xor(ts, 16);
      ts += __shfl_xor(ts, 32);
      l_[nt] = l_[nt] * alpha[nt] + ts;
    }
#pragma unroll
    for (int mt = 0; mt < 4; mt++)
#pragma unroll
      for (int nt = 0; nt < 2; nt++)
#pragma unroll
        for (int r = 0; r < 4; r++) oacc[mt][nt][r] *= alpha[nt];

    // Wave-level fence: Ps is wave-private (R2/R5 post-mortems).
    __asm__ volatile("s_waitcnt lgkmcnt(0)" ::: "memory");

    // ---- O^T += V^T @ P^T
#pragma unroll
    for (int kk = 0; kk < 2; kk++) {
      bf16x8 vf[4], pf[2];
#pragma unroll
      for (int mt = 0; mt < 4; mt++) {
        int row = mt * 16 + l16;
        vf[mt] = *(const bf16x8*)(&Vs[p][0] + row * 64 +
                                  (((kk * 4 + quad) ^ (row & 7)) * 8));
      }
#pragma unroll
      for (int nt = 0; nt < 2; nt++)
        pf[nt] = *(const bf16x8*)(&Ps[wave][(nt * 16 + l16) * 72 +
                                            kk * 32 + quad * 8]);
#pragma unroll
      for (int mt = 0; mt < 4; mt++)
#pragma unroll
        for (int nt = 0; nt < 2; nt++)
          oacc[mt][nt] = __builtin_amdgcn_mfma_f32_16x16x32_bf16(
              vf[mt], pf[nt], oacc[mt][nt], 0, 0, 0);
    }

    __syncthreads();   // reads of buf p done; kt+1's stage (vmcnt) drained
  }

  // ---- write O (un-transposing: per lane 4 consecutive hid cols)
#pragma unroll
  for (int nt = 0; nt < 2; nt++) {
    float rl = 1.0f / l_[nt];
#pragma unroll
    for (int mt = 0; mt < 4; mt++) {
      bf16x4 o4;
#pragma unroll
      for (int r = 0; r < 4; r++) o4[r] = (bf16)(oacc[mt][nt][r] * rl);
      *(bf16x4*)(o + ((size_t)(b * SEQ + qbase + nt * 16 + l16)) * NHID +
                 h * HDIM + mt * 16 + quad * 4) = o4;
    }
  }
}

// ---------------------------------------------------------------------------
// Workspace layout (bytes). Total ~136.2 MiB.
// wqT/wkT/wvT contiguous -> one [3072][1024] QKV weight matrix.
// ---------------------------------------------------------------------------
#define OFF_CMOD 0u
#define OFF_WQT  196608u
#define OFF_WKT  (OFF_WQT + 2097152u)
#define OFF_WVT  (OFF_WKT + 2097152u)
#define OFF_WOT  (OFF_WVT + 2097152u)
#define OFF_W1T  (OFF_WOT + 2097152u)
#define OFF_W2T  (OFF_W1T + 8388608u)
#define OFF_X2   (OFF_W2T + 8388608u)
#define OFF_XM2  (OFF_X2  + 33554432u)
#define OFF_POOL (OFF_XM2 + 16777216u)
// pool (67.1 MB): xm @ +0, q @ +16M, k @ +32M, vt @ +48M.
// o aliases xm (dead after QKV GEMM); h aliases whole pool.

extern "C" void kernel_launch(void* const* d_in, const int* in_sizes, int n_in,
                              void* d_out, int out_size, void* d_ws, size_t ws_size,
                              hipStream_t stream)
{
  const float* x     = (const float*)d_in[0];
  const float* c     = (const float*)d_in[1];
  const float* w_ada = (const float*)d_in[2];
  const float* b_ada = (const float*)d_in[3];
  const float* wq = (const float*)d_in[4];  const float* bq = (const float*)d_in[5];
  const float* wk = (const float*)d_in[6];  const float* bk = (const float*)d_in[7];
  const float* wv = (const float*)d_in[8];  const float* bv = (const float*)d_in[9];
  const float* wo = (const float*)d_in[10]; const float* bo = (const float*)d_in[11];
  const float* w1 = (const float*)d_in[12]; const float* b1 = (const float*)d_in[13];
  const float* w2 = (const float*)d_in[14]; const float* b2 = (const float*)d_in[15];
  float* out = (float*)d_out;
  char* ws = (char*)d_ws;

  float* cmod = (float*)(ws + OFF_CMOD);
  bf16* wqT = (bf16*)(ws + OFF_WQT);     // base of contiguous [3072][1024]
  bf16* wkT = (bf16*)(ws + OFF_WKT);
  bf16* wvT = (bf16*)(ws + OFF_WVT);
  bf16* woT = (bf16*)(ws + OFF_WOT);
  bf16* w1T = (bf16*)(ws + OFF_W1T);
  bf16* w2T = (bf16*)(ws + OFF_W2T);
  float* x2 = (float*)(ws + OFF_X2);
  bf16* xm2 = (bf16*)(ws + OFF_XM2);
  bf16* xm  = (bf16*)(ws + OFF_POOL);
  bf16* qb  = (bf16*)(ws + OFF_POOL + 16777216u);
  bf16* kb  = (bf16*)(ws + OFF_POOL + 33554432u);
  bf16* vtb = (bf16*)(ws + OFF_POOL + 50331648u);
  bf16* ob  = xm;   // alias
  bf16* hb  = xm;   // alias (covers 64 MB of pool)

  static bool attr_set = false;
  if (!attr_set) {
    hipFuncSetAttribute(reinterpret_cast<const void*>(&gemm8<5, 128>),
                        hipFuncAttributeMaxDynamicSharedMemorySize, 98304);
    hipFuncSetAttribute(reinterpret_cast<const void*>(&gemm8<1, 128>),
                        hipFuncAttributeMaxDynamicSharedMemorySize, 98304);
    hipFuncSetAttribute(reinterpret_cast<const void*>(&gemm8<2, 256>),
                        hipFuncAttributeMaxDynamicSharedMemorySize, 131072);
    hipFuncSetAttribute(reinterpret_cast<const void*>(&gemm8<3, 128>),
                        hipFuncAttributeMaxDynamicSharedMemorySize, 98304);
    attr_set = true;
  }

  TP4 tp;
  tp.s[0] = wq; tp.s[1] = wk; tp.s[2] = wv; tp.s[3] = wo;
  tp.d[0] = wqT; tp.d[1] = wkT; tp.d[2] = wvT; tp.d[3] = woT;
  transpose_conv4<<<dim3(32, 32, 4), 256, 0, stream>>>(tp);
  transpose_conv<<<dim3(128, 32), 256, 0, stream>>>(w1, w1T, 1024, 4096);
  transpose_conv<<<dim3(32, 128), 256, 0, stream>>>(w2, w2T, 4096, 1024);

  // cmod = 0, then ada accumulates k-split partials (+bias from z==0)
  hipMemsetAsync(cmod, 0, 196608u, stream);
  ada_kernel<<<dim3(24, 8, 4), 256, 0, stream>>>(c, w_ada, b_ada, cmod);

  // ln1 + modulate (sh_msa @ 0, sc_msa @ 1024)
  ln_mod<<<8192, 256, 0, stream>>>(x, cmod, xm, 0, 1024);

  // fused QKV: N=3072; q/k normal, v transposed (vt[b][hid][seq])
  // grid = GX*32 1D, GX = 24
  gemm8<5, 128><<<768, 512, 98304, stream>>>(
      xm, wqT, bq, bk, bv, qb, kb, vtb, nullptr, nullptr, 0, nullptr,
      1024, 1024);

  // attention: 512 blocks (4 qt x 16 h x 8 b), 512 threads
  attn_mfma<<<512, 512, 0, stream>>>(qb, kb, vtb, ob);

  // x2 = x + g_msa * (o @ wo + bo)      (g_msa @ 2048)  GX = 8
  gemm8<1, 128><<<256, 512, 98304, stream>>>(
      ob, woT, bo, nullptr, nullptr, nullptr, nullptr, nullptr, x2,
      cmod, 2048, x, 1024, 1024);

  // ln2 + modulate (sh_mlp @ 3072, sc_mlp @ 4096)
  ln_mod<<<8192, 256, 0, stream>>>(x2, cmod, xm2, 3072, 4096);

  // h = gelu(xm2 @ w1 + b1)   (tanh form)  GX = 16
  gemm8<2, 256><<<512, 512, 131072, stream>>>(
      xm2, w1T, b1, nullptr, nullptr, hb, nullptr, nullptr, nullptr,
      nullptr, 0, nullptr, 4096, 1024);

  // out = x2 + g_mlp * (h @ w2 + b2)    (g_mlp @ 5120)  GX = 8
  gemm8<3, 128><<<256, 512, 98304, stream>>>(
      hb, w2T, b2, nullptr, nullptr, nullptr, nullptr, nullptr, out,
      cmod, 5120, x2, 1024, 4096);
}

// Round 10
// 499.907 us; speedup vs baseline: 1.1023x; 1.0064x over previous
//
#include <hip/hip_runtime.h>
#include <hip/hip_bf16.h>
#include <cstdint>

// DiT block: B=8, N=1024, HID=1024, NH=16, HD=64, MLP=4096.
// R16: attention-only changes on the R15 base (503.1 us):
// (1) T13 defer-max: skip O-rescale + max-update when
//     __all(pmax - m <= 8) for both q-groups (P bounded by e^8, bf16-safe;
//     l_/oacc stay mutually consistent under stale m).
// (2) T5 s_setprio(1) around QK^T and PV MFMA clusters (attn waves are
//     phase-independent -> scheduler can favor MFMA-entering waves;
//     measured +4-7% on attn, null on lockstep GEMM).
// GEMMs / ln_mod / ada / transposes byte-identical to R15.

typedef __bf16 bf16;
typedef __attribute__((ext_vector_type(8))) __bf16 bf16x8;
typedef __attribute__((ext_vector_type(4))) __bf16 bf16x4;
typedef __attribute__((ext_vector_type(4))) float f32x4;

#define SEQ   1024
#define NHID  1024
#define NHEAD 16
#define HDIM  64
#define CMS   6144          // cmod row stride

// async 16B global->LDS: lds dest = wave-uniform base + lane*16
#define GLD16(gp, lp)                                                  \
  __builtin_amdgcn_global_load_lds(                                    \
      (const __attribute__((address_space(1))) void*)(gp),             \
      (__attribute__((address_space(3))) void*)(lp), 16, 0, 0)

template <int N> __device__ __forceinline__ void vmwait() {
  if constexpr (N == 0)      asm volatile("s_waitcnt vmcnt(0)" ::: "memory");
  else if constexpr (N == 4) asm volatile("s_waitcnt vmcnt(4)" ::: "memory");
  else if constexpr (N == 6) asm volatile("s_waitcnt vmcnt(6)" ::: "memory");
}

#define BAR()                                                          \
  { asm volatile("" ::: "memory");                                     \
    __builtin_amdgcn_s_barrier();                                      \
    asm volatile("" ::: "memory"); }

#define LGKM0() asm volatile("s_waitcnt lgkmcnt(0)" ::: "memory")

// ---------------------------------------------------------------------------
// Batched transpose + fp32->bf16 convert for four 1024x1024 weights.
// ---------------------------------------------------------------------------
struct TP4 { const float* s[4]; bf16* d[4]; };

__global__ __launch_bounds__(256) void transpose_conv4(TP4 p)
{
  __shared__ float tile[32][33];
  const float* __restrict__ src = p.s[blockIdx.z];
  bf16* __restrict__ dst = p.d[blockIdx.z];
  int n0 = blockIdx.x * 32, k0 = blockIdx.y * 32;
  int tx = threadIdx.x & 31, ty = threadIdx.x >> 5;
#pragma unroll
  for (int i = 0; i < 32; i += 8)
    tile[ty + i][tx] = src[(size_t)(k0 + ty + i) * 1024 + n0 + tx];
  __syncthreads();
#pragma unroll
  for (int i = 0; i < 32; i += 8)
    dst[(size_t)(n0 + ty + i) * 1024 + k0 + tx] = (bf16)tile[tx][ty + i];
}

__global__ __launch_bounds__(256) void transpose_conv(
    const float* __restrict__ src, bf16* __restrict__ dst, int K, int N)
{
  __shared__ float tile[32][33];
  int n0 = blockIdx.x * 32, k0 = blockIdx.y * 32;
  int tx = threadIdx.x & 31, ty = threadIdx.x >> 5;
#pragma unroll
  for (int i = 0; i < 32; i += 8)
    tile[ty + i][tx] = src[(size_t)(k0 + ty + i) * N + n0 + tx];
  __syncthreads();
#pragma unroll
  for (int i = 0; i < 32; i += 8)
    dst[(size_t)(n0 + ty + i) * K + k0 + tx] = (bf16)tile[tx][ty + i];
}

// ---------------------------------------------------------------------------
// cmod = silu(c) @ w_ada + b_ada      c:[8][1024]  w_ada:[1024][6144]
// k-split x4, grid (24, 8, 4); cmod pre-zeroed; atomicAdd fp32.
// ---------------------------------------------------------------------------
__global__ __launch_bounds__(256) void ada_kernel(
    const float* __restrict__ c, const float* __restrict__ w_ada,
    const float* __restrict__ b_ada, float* __restrict__ cmod)
{
  __shared__ float cs[256];
  const int b  = blockIdx.y;
  const int k0 = blockIdx.z * 256;
  const int col = blockIdx.x * 256 + threadIdx.x;
  {
    float cv = c[b * 1024 + k0 + threadIdx.x];
    cs[threadIdx.x] = cv / (1.0f + __expf(-cv));
  }
  __syncthreads();
  float acc = (blockIdx.z == 0) ? b_ada[col] : 0.0f;
#pragma unroll 8
  for (int kk = 0; kk < 256; kk++)
    acc += cs[kk] * w_ada[(size_t)(k0 + kk) * CMS + col];
  atomicAdd(&cmod[b * CMS + col], acc);
}

// ---------------------------------------------------------------------------
// LayerNorm (no affine) + modulate -> bf16.  One block per row.
// ---------------------------------------------------------------------------
__global__ __launch_bounds__(256) void ln_mod(
    const float* __restrict__ x, const float* __restrict__ cmod,
    bf16* __restrict__ out, int sh_off, int sc_off)
{
  int row = blockIdx.x, b = row >> 10, tid = threadIdx.x;
  const float4* xr = (const float4*)(x + (size_t)row * NHID);
  float4 v = xr[tid];
  float s  = v.x + v.y + v.z + v.w;
  float s2 = v.x * v.x + v.y * v.y + v.z * v.z + v.w * v.w;
#pragma unroll
  for (int off = 32; off; off >>= 1) {
    s  += __shfl_xor(s, off);
    s2 += __shfl_xor(s2, off);
  }
  __shared__ float red1[4], red2[4];
  int wave = tid >> 6, lane = tid & 63;
  if (lane == 0) { red1[wave] = s; red2[wave] = s2; }
  __syncthreads();
  float S  = red1[0] + red1[1] + red1[2] + red1[3];
  float S2 = red2[0] + red2[1] + red2[2] + red2[3];
  float mean = S * (1.0f / NHID);
  float var  = S2 * (1.0f / NHID) - mean * mean;
  float rs   = rsqrtf(var + 1e-6f);
  const float4* shp = (const float4*)(cmod + b * CMS + sh_off);
  const float4* scp = (const float4*)(cmod + b * CMS + sc_off);
  float4 sh4 = shp[tid], sc4 = scp[tid];
  bf16x4 o4;
  o4[0] = (bf16)((v.x - mean) * rs * (1.0f + sc4.x) + sh4.x);
  o4[1] = (bf16)((v.y - mean) * rs * (1.0f + sc4.y) + sh4.y);
  o4[2] = (bf16)((v.z - mean) * rs * (1.0f + sc4.z) + sh4.z);
  o4[3] = (bf16)((v.w - mean) * rs * (1.0f + sc4.w) + sh4.w);
  *(bf16x4*)(out + (size_t)row * NHID + tid * 4) = o4;
}

// ---------------------------------------------------------------------------
// 8-phase 256-row GEMM, m201-ordered slots, register fragment reuse,
// XCD supertile swizzle (R10/R12 — unchanged). 1D grid of GX*32 blocks.
// xcd = bid&7 owns by in [xcd*4, xcd*4+4), bx sweeps 0..GX.
// 8 waves: BN=256 -> 2Mx4N (per-wave 128x64); BN=128 -> 4Mx2N (64x64).
// LDS: A = 2buf x 2half(128 rows) x 64k; B = 2buf x 2half(BN/2 rows) x 64k.
// XOR swizzle: 16B slot s of row r holds k-chunk s^(r&7).
// EPI: 1/3 = fp32 out = resid + gate*val; 2 = bf16 tanh-gelu;
//      5 = fused QKV (col<1024 q, <2048 k, else v transposed).
// ---------------------------------------------------------------------------
template <int EPI, int BN>
__global__ __launch_bounds__(512, 2) void gemm8(
    const bf16* __restrict__ A, const bf16* __restrict__ Bt,
    const float* __restrict__ bias, const float* __restrict__ bias2,
    const float* __restrict__ bias3,
    bf16* __restrict__ outb, bf16* __restrict__ outb2,
    bf16* __restrict__ outb3, float* __restrict__ outf,
    const float* __restrict__ cmod, int gate_off,
    const float* __restrict__ resid,
    int N, int K)
{
  constexpr int BNH   = BN / 2;        // rows per B half-region
  constexpr int LB    = BNH / 64;      // gld16 per thread per B half (2 or 1)
  constexpr int MF    = BN / 64;       // A m-frags per slot (4 or 2)
  constexpr int WC    = BN / 64;       // waves along N (4 or 2)
  constexpr int WRS   = 256 / (8 / WC) / 2;  // per-wave A row span (64 or 32)
  constexpr int VMN   = (LB == 2) ? 6 : 4;   // once-per-K-tile gate
  constexpr int BOFF  = 65536;         // LDS offset of B
  constexpr int BBUF  = BNH * 256;     // B bytes per buffer
  constexpr int BHALF = BNH * 128;     // B bytes per half-region

  extern __shared__ __align__(16) char smem[];

  const int tid  = threadIdx.x;
  // ---- XCD supertile decode: xcd owns 4 consecutive by rows, all bx ----
  const int xcd  = blockIdx.x & 7;
  const int slot = blockIdx.x >> 3;
  const int by   = xcd * 4 + (slot & 3);
  const int bx   = slot >> 2;
  const int bm = by * 256, bn = bx * BN;

  const int wave = tid >> 6, lane = tid & 63;
  const int wr = wave / WC, wc = wave % WC;
  const int l16 = lane & 15, q4 = lane >> 4;

  // staging: thread -> (row rq [+64], 16B slot tid&7), chunk pre-XOR'd
  const int rq = tid >> 3;
  const int ch = ((tid & 7) ^ (rq & 7)) * 8;
  const int wbase = (tid & 448) * 16;          // wave-uniform LDS base

  // ds_read bases: row&7 == l16&7 for all frags (row offsets mult of 16/32)
  const int aRowB = (wr * WRS + l16) * 128;
  const int bRowB = (wc * 32 + l16) * 128;
  const int slotB = (q4 ^ (l16 & 7)) * 16;

  f32x4 acc[2][2][MF][2];
#pragma unroll
  for (int a0 = 0; a0 < 2; a0++)
#pragma unroll
    for (int a1 = 0; a1 < 2; a1++)
#pragma unroll
      for (int a2 = 0; a2 < MF; a2++)
#pragma unroll
        for (int a3 = 0; a3 < 2; a3++) acc[a0][a1][a2][a3] = (f32x4)0.0f;

  auto stA = [&](int buf, int half, int T) {
    const bf16* g = A + (size_t)(bm + half * 128 + rq) * K + T * 64 + ch;
    char* l = smem + buf * 32768 + half * 16384 + wbase;
    GLD16(g, l);
    GLD16(g + (size_t)64 * K, l + 8192);
  };
  auto stB = [&](int buf, int half, int T) {
    const bf16* g = Bt + (size_t)(bn + half * BNH + rq) * K + T * 64 + ch;
    char* l = smem + BOFF + buf * BBUF + half * BHALF + wbase;
    GLD16(g, l);
    if constexpr (LB == 2) { GLD16(g + (size_t)64 * K, l + 8192); }
  };

#define RDA(BUF, QM, FR)                                                   \
  { const char* ab_ = smem + (BUF) * 32768 + (QM) * 16384 + aRowB;         \
    _Pragma("unroll")                                                      \
    for (int ks = 0; ks < 2; ks++) {                                       \
      const int sb_ = slotB ^ (ks * 64);                                   \
      _Pragma("unroll")                                                    \
      for (int mf = 0; mf < MF; mf++)                                      \
        FR[ks][mf] = *(const bf16x8*)(ab_ + mf * 2048 + sb_);              \
    } }

#define RDB(BUF, QN, FR)                                                   \
  { const char* bb_ = smem + BOFF + (BUF) * BBUF + (QN) * BHALF + bRowB;   \
    _Pragma("unroll")                                                      \
    for (int ks = 0; ks < 2; ks++) {                                       \
      const int sb_ = slotB ^ (ks * 64);                                   \
      _Pragma("unroll")                                                    \
      for (int nf = 0; nf < 2; nf++)                                       \
        FR[ks][nf] = *(const bf16x8*)(bb_ + nf * 2048 + sb_);              \
    } }

#define MM(QM, QN, AF, BF)                                                 \
  { __builtin_amdgcn_s_setprio(1);                                         \
    _Pragma("unroll")                                                      \
    for (int mf = 0; mf < MF; mf++)                                        \
      _Pragma("unroll")                                                    \
      for (int nf = 0; nf < 2; nf++) {                                     \
        acc[QM][QN][mf][nf] = __builtin_amdgcn_mfma_f32_16x16x32_bf16(     \
            AF[0][mf], BF[0][nf], acc[QM][QN][mf][nf], 0, 0, 0);           \
        acc[QM][QN][mf][nf] = __builtin_amdgcn_mfma_f32_16x16x32_bf16(     \
            AF[1][mf], BF[1][nf], acc[QM][QN][mf][nf], 0, 0, 0);           \
      }                                                                    \
    __builtin_amdgcn_s_setprio(0); }

  const int NT = K >> 6, NI = NT >> 1;

  bf16x8 afr[2][MF], bfr0[2][2], bfr1[2][2];

  // prologue: tile0 fully, tile1 all but A1 (A1(1) staged at s1 of tile 0)
  stA(0, 0, 0); stB(0, 0, 0); stB(0, 1, 0); stA(0, 1, 0);
  stA(1, 0, 1); stB(1, 0, 1); stB(1, 1, 1);
  vmwait<VMN>();
  BAR();

  for (int i = 0; i < NI; ++i) {
    const int t = 2 * i;
    const int u2 = (t + 2 < NT) ? t + 2 : NT - 2;  // clamp: dead, L2-hot
    const int u3 = (t + 3 < NT) ? t + 3 : NT - 1;
    // ---- tile t (buf0)
    RDA(0, 0, afr); RDB(0, 0, bfr0);
    stA(1, 1, t + 1);
    BAR(); LGKM0();
    MM(0, 0, afr, bfr0);
    BAR();
    RDB(0, 1, bfr1);
    stA(0, 0, u2);
    BAR(); LGKM0();
    MM(0, 1, afr, bfr1);
    BAR();
    RDA(0, 1, afr);
    stB(0, 0, u2);
    BAR(); LGKM0();
    MM(1, 1, afr, bfr1);
    BAR();
    stB(0, 1, u2);
    vmwait<VMN>();
    BAR();
    MM(1, 0, afr, bfr0);
    BAR();
    // ---- tile t+1 (buf1)
    RDA(1, 0, afr); RDB(1, 0, bfr0);
    stA(0, 1, u2);
    BAR(); LGKM0();
    MM(0, 0, afr, bfr0);
    BAR();
    RDB(1, 1, bfr1);
    stA(1, 0, u3);
    BAR(); LGKM0();
    MM(0, 1, afr, bfr1);
    BAR();
    RDA(1, 1, afr);
    stB(1, 0, u3);
    BAR(); LGKM0();
    MM(1, 1, afr, bfr1);
    BAR();
    stB(1, 1, u3);
    vmwait<VMN>();
    BAR();
    MM(1, 0, afr, bfr0);
    BAR();
  }
  vmwait<0>();
#undef RDA
#undef RDB
#undef MM

  // ---- epilogue ----
  const int colBase = bn + wc * 32 + l16;
  const int rowBase = bm + wr * WRS + q4 * 4;
#pragma unroll
  for (int qm = 0; qm < 2; qm++)
#pragma unroll
  for (int qn = 0; qn < 2; qn++)
#pragma unroll
  for (int mf = 0; mf < MF; mf++)
#pragma unroll
  for (int nf = 0; nf < 2; nf++) {
    const int col  = colBase + qn * BNH + nf * 16;
    const int row0 = rowBase + qm * 128 + mf * 16;
    f32x4 v = acc[qm][qn][mf][nf];
    if constexpr (EPI == 5) {
      const int sel = bn >> 10;          // block-uniform (BN<=256 aligned)
      const float* bp = (sel == 0) ? bias : (sel == 1) ? bias2 : bias3;
      const int colq = col & 1023;
      const float bcol = bp[colq];
      if (sel == 2) {
        // V: transposed write vt[b][hid][seq]; 4 consecutive seq rows
        bf16x4 o4;
#pragma unroll
        for (int r = 0; r < 4; r++) o4[r] = (bf16)(v[r] + bcol);
        const int bidx = row0 >> 10;
        *(bf16x4*)(outb3 + ((size_t)bidx * NHID + colq) * SEQ +
                   (row0 & 1023)) = o4;
      } else {
        bf16* qk = (sel == 0) ? outb : outb2;
#pragma unroll
        for (int r = 0; r < 4; r++)
          qk[(size_t)(row0 + r) * 1024 + colq] = (bf16)(v[r] + bcol);
      }
    } else if constexpr (EPI == 2) {
      const float bcol = bias[col];
#pragma unroll
      for (int r = 0; r < 4; r++) {
        float val = v[r] + bcol;
        float u2g = 2.0f * val * (0.7978845608f + 0.0356774081f * val * val);
        float e = __expf(u2g);
        float th = 1.0f - 2.0f / (e + 1.0f);
        outb[(size_t)(row0 + r) * N + col] = (bf16)(0.5f * val * (1.0f + th));
      }
    } else {  // EPI 1 / 3: fp32 out = resid + gate*val
      const float bcol = bias[col];
#pragma unroll
      for (int r = 0; r < 4; r++) {
        const int row = row0 + r;
        const float gg = cmod[(row >> 10) * CMS + gate_off + col];
        outf[(size_t)row * N + col] =
            resid[(size_t)row * N + col] + gg * (v[r] + bcol);
      }
    }
  }
}

// ---------------------------------------------------------------------------
// MFMA flash attention. R16: K/V double-buffered (R15) + T13 defer-max
// (skip O-rescale when __all(pmax - m <= 8) for both q-groups) + T5
// setprio around the QK^T and PV MFMA clusters.
// 512 blocks (4 qt x 16 h x 8 b), 512 threads, 256 q-rows per block.
// LDS: Ks 16KB + Vs 16KB + Ps 36KB = 68KB -> 2 blocks/CU.
// ---------------------------------------------------------------------------
__global__ __launch_bounds__(512) void attn_mfma(
    const bf16* __restrict__ q, const bf16* __restrict__ k,
    const bf16* __restrict__ vt, bf16* __restrict__ o)
{
  __shared__ __align__(16) bf16 Ks[2][64 * 64];
  __shared__ __align__(16) bf16 Vs[2][64 * 64];
  __shared__ __align__(16) bf16 Ps[8][32 * 72];   // [wave][qloc][key] stride 72

  int bid = blockIdx.x;
  int qt = bid & 3, h = (bid >> 2) & 15, b = bid >> 6;
  int tid = threadIdx.x, wave = tid >> 6, lane = tid & 63;
  int quad = lane >> 4, l16 = lane & 15;
  int qbase = qt * 256 + wave * 32;

  bf16x8 qf[2][2];
  const bf16* qp = q + ((size_t)(b * SEQ + qbase)) * NHID + h * HDIM;
#pragma unroll
  for (int nt = 0; nt < 2; nt++)
#pragma unroll
    for (int kk = 0; kk < 2; kk++) {
      bf16x8 t = *(const bf16x8*)(qp + (size_t)(nt * 16 + l16) * NHID +
                                  kk * 32 + quad * 8);
#pragma unroll
      for (int j = 0; j < 8; j++) t[j] = (bf16)((float)t[j] * 0.015625f);
      qf[nt][kk] = t;
    }

  f32x4 oacc[4][2];
#pragma unroll
  for (int mt = 0; mt < 4; mt++)
#pragma unroll
    for (int nt = 0; nt < 2; nt++) oacc[mt][nt] = (f32x4)0.0f;
  float m_[2] = {-3.0e38f, -3.0e38f}, l_[2] = {0.0f, 0.0f};

  const bf16* kb = k + ((size_t)(b * SEQ)) * NHID + h * HDIM;
  const bf16* vb = vt + ((size_t)(b * NHID + h * HDIM)) * SEQ;

  // 512-thread staging: rq in [0,64), one GLD16 per matrix per thread
  const int sr0 = tid >> 3, sc0 = tid & 7;
  const int cg0 = (sc0 ^ (sr0 & 7)) * 8;
  const int lofs = (tid & 448) * 8;           // wave-uniform element base

  auto stage = [&](int p, int kt) {
    GLD16(kb + (size_t)(kt * 64 + sr0) * NHID + cg0, &Ks[p][0] + lofs);
    GLD16(vb + (size_t)sr0 * SEQ + kt * 64 + cg0, &Vs[p][0] + lofs);
  };

  stage(0, 0);
  __syncthreads();      // implicit vmcnt(0): buf0 ready

  for (int kt = 0; kt < 16; kt++) {
    const int p = kt & 1;
    if (kt + 1 < 16) stage(p ^ 1, kt + 1);

    // ---- S^T = K @ Q^T  (already scaled via qf)
    f32x4 sacc[4][2];
#pragma unroll
    for (int mt = 0; mt < 4; mt++)
#pragma unroll
      for (int nt = 0; nt < 2; nt++) sacc[mt][nt] = (f32x4)0.0f;
#pragma unroll
    for (int kk = 0; kk < 2; kk++) {
      bf16x8 kf[4];
#pragma unroll
      for (int mt = 0; mt < 4; mt++) {
        int row = mt * 16 + l16;
        kf[mt] = *(const bf16x8*)(&Ks[p][0] + row * 64 +
                                  (((kk * 4 + quad) ^ (row & 7)) * 8));
      }
      __builtin_amdgcn_s_setprio(1);
#pragma unroll
      for (int mt = 0; mt < 4; mt++)
#pragma unroll
        for (int nt = 0; nt < 2; nt++)
          sacc[mt][nt] = __builtin_amdgcn_mfma_f32_16x16x32_bf16(
              kf[mt], qf[nt][kk], sacc[mt][nt], 0, 0, 0);
      __builtin_amdgcn_s_setprio(0);
    }

    // ---- online softmax with T13 defer-max (per q column = (nt, l16))
    float tm[2];
#pragma unroll
    for (int nt = 0; nt < 2; nt++) {
      float t0 = -3.0e38f;
#pragma unroll
      for (int mt = 0; mt < 4; mt++)
#pragma unroll
        for (int r = 0; r < 4; r++) t0 = fmaxf(t0, sacc[mt][nt][r]);
      t0 = fmaxf(t0, __shfl_xor(t0, 16));
      t0 = fmaxf(t0, __shfl_xor(t0, 32));
      tm[nt] = t0;
    }
    const bool need = !__all(tm[0] - m_[0] <= 8.0f &&
                             tm[1] - m_[1] <= 8.0f);
    if (need) {
#pragma unroll
      for (int nt = 0; nt < 2; nt++) {
        float mn = fmaxf(m_[nt], tm[nt]);
        float alpha = __expf(m_[nt] - mn);
        m_[nt] = mn;
        l_[nt] *= alpha;
#pragma unroll
        for (int mt = 0; mt < 4; mt++)
#pragma unroll
          for (int r = 0; r < 4; r++) oacc[mt][nt][r] *= alpha;
      }
    }
#pragma unroll
    for (int nt = 0; nt < 2; nt++) {
      float ts = 0.0f;
#pragma unroll
      for (int mt = 0; mt < 4; mt++) {
        bf16x4 pv;
#pragma unroll
        for (int r = 0; r < 4; r++) {
          float p2 = __expf(sacc[mt][nt][r] - m_[nt]);
          ts += p2;
          pv[r] = (bf16)p2;
        }
        *(bf16x4*)(&Ps[wave][(nt * 16 + l16) * 72 + mt * 16 + quad * 4]) = pv;
      }
      ts += __shfl_xor(ts, 16);
      ts += __shfl_xor(ts, 32);
      l_[nt] += ts;
    }

    // Wave-level fence: Ps is wave-private (R2/R5 post-mortems).
    __asm__ volatile("s_waitcnt lgkmcnt(0)" ::: "memory");

    // ---- O^T += V^T @ P^T
#pragma unroll
    for (int kk = 0; kk < 2; kk++) {
      bf16x8 vf[4], pf[2];
#pragma unroll
      for (int mt = 0; mt < 4; mt++) {
        int row = mt * 16 + l16;
        vf[mt] = *(const bf16x8*)(&Vs[p][0] + row * 64 +
                                  (((kk * 4 + quad) ^ (row & 7)) * 8));
      }
#pragma unroll
      for (int nt = 0; nt < 2; nt++)
        pf[nt] = *(const bf16x8*)(&Ps[wave][(nt * 16 + l16) * 72 +
                                            kk * 32 + quad * 8]);
      __builtin_amdgcn_s_setprio(1);
#pragma unroll
      for (int mt = 0; mt < 4; mt++)
#pragma unroll
        for (int nt = 0; nt < 2; nt++)
          oacc[mt][nt] = __builtin_amdgcn_mfma_f32_16x16x32_bf16(
              vf[mt], pf[nt], oacc[mt][nt], 0, 0, 0);
      __builtin_amdgcn_s_setprio(0);
    }

    __syncthreads();   // reads of buf p done; kt+1's stage (vmcnt) drained
  }

  // ---- write O (un-transposing: per lane 4 consecutive hid cols)
#pragma unroll
  for (int nt = 0; nt < 2; nt++) {
    float rl = 1.0f / l_[nt];
#pragma unroll
    for (int mt = 0; mt < 4; mt++) {
      bf16x4 o4;
#pragma unroll
      for (int r = 0; r < 4; r++) o4[r] = (bf16)(oacc[mt][nt][r] * rl);
      *(bf16x4*)(o + ((size_t)(b * SEQ + qbase + nt * 16 + l16)) * NHID +
                 h * HDIM + mt * 16 + quad * 4) = o4;
    }
  }
}

// ---------------------------------------------------------------------------
// Workspace layout (bytes). Total ~136.2 MiB.
// wqT/wkT/wvT contiguous -> one [3072][1024] QKV weight matrix.
// ---------------------------------------------------------------------------
#define OFF_CMOD 0u
#define OFF_WQT  196608u
#define OFF_WKT  (OFF_WQT + 2097152u)
#define OFF_WVT  (OFF_WKT + 2097152u)
#define OFF_WOT  (OFF_WVT + 2097152u)
#define OFF_W1T  (OFF_WOT + 2097152u)
#define OFF_W2T  (OFF_W1T + 8388608u)
#define OFF_X2   (OFF_W2T + 8388608u)
#define OFF_XM2  (OFF_X2  + 33554432u)
#define OFF_POOL (OFF_XM2 + 16777216u)
// pool (67.1 MB): xm @ +0, q @ +16M, k @ +32M, vt @ +48M.
// o aliases xm (dead after QKV GEMM); h aliases whole pool.

extern "C" void kernel_launch(void* const* d_in, const int* in_sizes, int n_in,
                              void* d_out, int out_size, void* d_ws, size_t ws_size,
                              hipStream_t stream)
{
  const float* x     = (const float*)d_in[0];
  const float* c     = (const float*)d_in[1];
  const float* w_ada = (const float*)d_in[2];
  const float* b_ada = (const float*)d_in[3];
  const float* wq = (const float*)d_in[4];  const float* bq = (const float*)d_in[5];
  const float* wk = (const float*)d_in[6];  const float* bk = (const float*)d_in[7];
  const float* wv = (const float*)d_in[8];  const float* bv = (const float*)d_in[9];
  const float* wo = (const float*)d_in[10]; const float* bo = (const float*)d_in[11];
  const float* w1 = (const float*)d_in[12]; const float* b1 = (const float*)d_in[13];
  const float* w2 = (const float*)d_in[14]; const float* b2 = (const float*)d_in[15];
  float* out = (float*)d_out;
  char* ws = (char*)d_ws;

  float* cmod = (float*)(ws + OFF_CMOD);
  bf16* wqT = (bf16*)(ws + OFF_WQT);     // base of contiguous [3072][1024]
  bf16* wkT = (bf16*)(ws + OFF_WKT);
  bf16* wvT = (bf16*)(ws + OFF_WVT);
  bf16* woT = (bf16*)(ws + OFF_WOT);
  bf16* w1T = (bf16*)(ws + OFF_W1T);
  bf16* w2T = (bf16*)(ws + OFF_W2T);
  float* x2 = (float*)(ws + OFF_X2);
  bf16* xm2 = (bf16*)(ws + OFF_XM2);
  bf16* xm  = (bf16*)(ws + OFF_POOL);
  bf16* qb  = (bf16*)(ws + OFF_POOL + 16777216u);
  bf16* kb  = (bf16*)(ws + OFF_POOL + 33554432u);
  bf16* vtb = (bf16*)(ws + OFF_POOL + 50331648u);
  bf16* ob  = xm;   // alias
  bf16* hb  = xm;   // alias (covers 64 MB of pool)

  static bool attr_set = false;
  if (!attr_set) {
    hipFuncSetAttribute(reinterpret_cast<const void*>(&gemm8<5, 128>),
                        hipFuncAttributeMaxDynamicSharedMemorySize, 98304);
    hipFuncSetAttribute(reinterpret_cast<const void*>(&gemm8<1, 128>),
                        hipFuncAttributeMaxDynamicSharedMemorySize, 98304);
    hipFuncSetAttribute(reinterpret_cast<const void*>(&gemm8<2, 256>),
                        hipFuncAttributeMaxDynamicSharedMemorySize, 131072);
    hipFuncSetAttribute(reinterpret_cast<const void*>(&gemm8<3, 128>),
                        hipFuncAttributeMaxDynamicSharedMemorySize, 98304);
    attr_set = true;
  }

  TP4 tp;
  tp.s[0] = wq; tp.s[1] = wk; tp.s[2] = wv; tp.s[3] = wo;
  tp.d[0] = wqT; tp.d[1] = wkT; tp.d[2] = wvT; tp.d[3] = woT;
  transpose_conv4<<<dim3(32, 32, 4), 256, 0, stream>>>(tp);
  transpose_conv<<<dim3(128, 32), 256, 0, stream>>>(w1, w1T, 1024, 4096);
  transpose_conv<<<dim3(32, 128), 256, 0, stream>>>(w2, w2T, 4096, 1024);

  // cmod = 0, then ada accumulates k-split partials (+bias from z==0)
  hipMemsetAsync(cmod, 0, 196608u, stream);
  ada_kernel<<<dim3(24, 8, 4), 256, 0, stream>>>(c, w_ada, b_ada, cmod);

  // ln1 + modulate (sh_msa @ 0, sc_msa @ 1024)
  ln_mod<<<8192, 256, 0, stream>>>(x, cmod, xm, 0, 1024);

  // fused QKV: N=3072; q/k normal, v transposed (vt[b][hid][seq])
  // grid = GX*32 1D, GX = 24
  gemm8<5, 128><<<768, 512, 98304, stream>>>(
      xm, wqT, bq, bk, bv, qb, kb, vtb, nullptr, nullptr, 0, nullptr,
      1024, 1024);

  // attention: 512 blocks (4 qt x 16 h x 8 b), 512 threads
  attn_mfma<<<512, 512, 0, stream>>>(qb, kb, vtb, ob);

  // x2 = x + g_msa * (o @ wo + bo)      (g_msa @ 2048)  GX = 8
  gemm8<1, 128><<<256, 512, 98304, stream>>>(
      ob, woT, bo, nullptr, nullptr, nullptr, nullptr, nullptr, x2,
      cmod, 2048, x, 1024, 1024);

  // ln2 + modulate (sh_mlp @ 3072, sc_mlp @ 4096)
  ln_mod<<<8192, 256, 0, stream>>>(x2, cmod, xm2, 3072, 4096);

  // h = gelu(xm2 @ w1 + b1)   (tanh form)  GX = 16
  gemm8<2, 256><<<512, 512, 131072, stream>>>(
      xm2, w1T, b1, nullptr, nullptr, hb, nullptr, nullptr, nullptr,
      nullptr, 0, nullptr, 4096, 1024);

  // out = x2 + g_mlp * (h @ w2 + b2)    (g_mlp @ 5120)  GX = 8
  gemm8<3, 128><<<256, 512, 98304, stream>>>(
      hb, w2T, b2, nullptr, nullptr, nullptr, nullptr, nullptr, out,
      cmod, 5120, x2, 1024, 4096);
}